// Round 6
// baseline (241.979 us; speedup 1.0000x reference)
//
#include <hip/hip_runtime.h>

#define H 8
#define NSEQ 4096
#define DIM 64
#define BATCH 8
#define AREV_LEN 4448   // 4096 lags + 352 zero pad (A prefetch depth-3 reads elem up to
                        // ~4430). 2224 dwords == 16 mod 32 -> shifted copy sits at bank
                        // offset +16 vs base copy: parity groups mostly disjoint banks.
#define AREV_DW (AREV_LEN/2)   // 2224
#define XPLEN 4144      // 16 front zeros (shifted-col reads) + 4096 + 32 tail pad.
#define HD (H*DIM)      // 512

typedef __attribute__((ext_vector_type(8))) short short8;
typedef __attribute__((ext_vector_type(4))) float float4v;
typedef __attribute__((ext_vector_type(4))) unsigned int uint4v;
typedef const __attribute__((address_space(1))) unsigned int* gas_u32p;
typedef __attribute__((address_space(3))) unsigned int* las_u32p;

__device__ inline unsigned short f32_to_bf16(float f) {
    unsigned int u = __float_as_uint(f);
    u += 0x7fffu + ((u >> 16) & 1u);   // RNE
    return (unsigned short)(u >> 16);
}

// ---- P1: arev[hd][i] = bf16( exp(clamp(log(gamma)*k + pos[k-1])) ) at k = 4095 - i ----
__global__ __launch_bounds__(256) void build_arev(
    const float* __restrict__ zero, const float* __restrict__ pos,
    const float* __restrict__ gamma, unsigned short* __restrict__ arev)
{
    __shared__ float lg[64];
    __shared__ unsigned short T[64][65];
    int h = blockIdx.y, kb = blockIdx.x;
    int tid = threadIdx.x;
    if (tid < 64) lg[tid] = logf(gamma[h*64 + tid]);
    __syncthreads();
    #pragma unroll
    for (int jj = 0; jj < 16; ++jj) {
        int e = tid + 256*jj;
        int kk = e >> 6, dd = e & 63;
        int k = kb*64 + kk;
        float v;
        if (k == 0) v = zero[h*64 + dd];
        else        v = lg[dd] * (float)k + pos[(h*4095 + (k-1))*64 + dd];
        v = fminf(30.f, fmaxf(-60.f, v));
        T[kk][dd] = f32_to_bf16(expf(v));
    }
    __syncthreads();
    int i0 = 4032 - kb*64;   // tile writes arev[hd][i0 .. i0+63], i = 4095 - k
    #pragma unroll
    for (int jj = 0; jj < 16; ++jj) {
        int e = tid + 256*jj;
        int dpr = e >> 6, ii = e & 63;
        arev[(size_t)(h*64 + dpr)*AREV_LEN + i0 + ii] = T[63 - ii][dpr];
    }
    unsigned short* pr = arev + (size_t)(h*64 + kb)*AREV_LEN + 4096;
    for (int i = tid; i < AREV_LEN - 4096; i += 256) pr[i] = 0;
}

// ---- P2: xp[hd][b][16 + s] = bf16(x[b][h][s][d]); rows front/tail zero-padded ----
__global__ __launch_bounds__(256) void build_xp(
    const float* __restrict__ x, unsigned short* __restrict__ xp)
{
    __shared__ unsigned short T[64][66];   // stride 66: dword-aligned, conflict-free cols
    int sb = blockIdx.x, h = blockIdx.y, b = blockIdx.z;
    int tid = threadIdx.x;
    const float4v* src4 =
        (const float4v*)(x + ((size_t)(b*H + h)*NSEQ + sb*64)*DIM);
    #pragma unroll
    for (int jj = 0; jj < 4; ++jj) {
        int e = tid + 256*jj;            // [0,1024)
        int ss = e >> 4, d4 = e & 15;
        float4v f = src4[ss*16 + d4];
        #pragma unroll
        for (int k = 0; k < 4; ++k) T[ss][4*d4 + k] = f32_to_bf16(f[k]);
    }
    __syncthreads();
    unsigned int* xp32 = (unsigned int*)xp;
    #pragma unroll
    for (int jj = 0; jj < 8; ++jj) {
        int e = tid + 256*jj;            // [0,2048)
        int dpr = e >> 5, c2 = e & 31;   // row d, dword col (2 s-elems)
        unsigned int lo = T[2*c2][dpr], hi = T[2*c2 + 1][dpr];
        size_t dwofs = (((size_t)(h*64 + dpr)*BATCH + b)*XPLEN + 16 + sb*64) >> 1;
        xp32[dwofs + c2] = lo | (hi << 16);
    }
    if (sb == 0) {
        for (int e = tid; e < 64*16; e += 256) {
            int dd = e >> 4, i = e & 15;
            xp[((size_t)(h*64 + dd)*BATCH + b)*XPLEN + i] = 0;
        }
    }
    if (sb == 63) {
        for (int e = tid; e < 64*32; e += 256) {
            int dd = e >> 5, i = e & 31;
            xp[((size_t)(h*64 + dd)*BATCH + b)*XPLEN + 16 + NSEQ + i] = 0;
        }
    }
}

// ---- GEMM: per (h,d): Out[t, 0:8] = sum_s a[t-s] * X[s, 0:8], causal ----
// One WG = one (h,d) + band pair {p,3-p}; every wave does exactly 136 k-steps.
// 20 windows of 256 s. Per window: stage window t+2's 8KB B tile (quad-buffered
// LDS, global_load_lds w16), counted-wait s_waitcnt vmcnt(4) + raw s_barrier
// (keeps 2 windows of loads in flight ACROSS barriers -- no full drain), then
// 8 k-steps of {1 A-ds_read_b32x4 (ring, depth-3 pipeline), 1 B-ds_read_b128
// (XOR-swizzled -> conflict-free), 8 MFMA}. B swizzle: global_load_lds writes
// LDS linearly, so the swizzle is applied by permuting each lane's GLOBAL
// source offset (8*(q'^((nb>>1)&3))); reader XORs the same term.
__global__ __launch_bounds__(256) void toeplitz_gemm(
    const unsigned short* __restrict__ arev,
    const unsigned short* __restrict__ xp,
    float* __restrict__ out)
{
    __shared__ unsigned int ldsA[2*AREV_DW];   // 17.8 KB: arev dwords + 1-elem shift
    __shared__ uint4v ldsB[4*512];             // 32 KB: quad-buffered 8KB B tiles

    // swizzle: 16 line-sharing consecutive-d WGs -> same XCD (id%8).
    int id = blockIdx.x;                 // [0, 1024)
    int q8 = id >> 7, rem = id & 127;
    int r  = rem >> 3, xx = rem & 7;
    int g  = q8*8 + xx;                  // [0, 64)
    int nlin = g*16 + r;                 // [0, 1024)
    int p  = nlin >> 9;                  // band pair: {p, 3-p}
    int h  = (nlin >> 6) & 7;
    int d  = nlin & 63;
    int hd = h*64 + d;

    int tid = threadIdx.x;
    const unsigned int* g32 = (const unsigned int*)(arev + (size_t)hd*AREV_LEN);
    int i0s = p << 9;                    // pair {1,2} never reads lag idx < 1024
    for (int i = i0s + tid; i < AREV_DW; i += 256) ldsA[i] = g32[i];
    for (int i = i0s + tid; i < AREV_DW - 1; i += 256)
        ldsA[AREV_DW + i] = (g32[i] >> 16) | (g32[i+1] << 16);  // elems 2i+1, 2i+2

    int w = tid >> 6, lane = tid & 63;
    int nb = lane & 15;        // A-frag row m and B-frag col n
    int q  = lane >> 4;        // k-quad
    int swz  = (nb >> 1) & 3;
    int bq16 = nb*4 + (q ^ swz);   // swizzled B-frag uint4 index within a chunk

    // staging source: lane l stages LDS piece (u=4c+w, nb=l>>2, q'=l&3);
    // source elem = S + 128c + 32w + 8*(q' ^ swz(nb)) in xp row nb.
    int rnb = lane >> 2, rq = lane & 3, rswz = (rnb >> 1) & 3;
    const unsigned short* xsrc =
        xp + ((size_t)hd*BATCH + (rnb & 7))*XPLEN + 16 - ((rnb >> 3) << 4)
           + w*32 + 8*(rq ^ rswz);

    int W1 = (p + 1) * 4;      // phase-1 windows; total = 20 for both pairs
    const int WT = 20;

    auto stg = [&](int t) {
        int S = ((t < W1) ? t : t - W1) << 8;
        __builtin_amdgcn_global_load_lds(
            (gas_u32p)(const void*)(xsrc + S),
            (las_u32p)(void*)&ldsB[(t & 3)*512 + w*64], 16, 0, 0);
        __builtin_amdgcn_global_load_lds(
            (gas_u32p)(const void*)(xsrc + S + 128),
            (las_u32p)(void*)&ldsB[(t & 3)*512 + 256 + w*64], 16, 0, 0);
    };

    int tsh = (nb >> 3) << 4;
    float* obase = out + ((size_t)((nb & 7)*H + h)*NSEQ)*DIM + d;

    // per-phase state
    float4v acc[8];
    short8 rg[8];
    short8 rn, rn2;
    int dwb = 0, s_end = 0, bW = 0;

    auto LFA = [&](int so) -> short8 {
        int dw = dwb + (so >> 1);    // so always even; parity folded into dwb
        union { short8 v; unsigned int u4[4]; } af;
        af.u4[0] = ldsA[dw];   af.u4[1] = ldsA[dw+1];
        af.u4[2] = ldsA[dw+2]; af.u4[3] = ldsA[dw+3];
        return af.v;
    };
    auto LFB = [&](int bb, int u) -> short8 {
        union { short8 v; uint4v u4; } bf_;
        bf_.u4 = ldsB[bb + u*64 + bq16];   // single ds_read_b128, 16B-aligned
        return bf_.v;
    };

    auto init_phase = [&](int b) {
        bW = b;
        s_end = b + 240;               // multiple of 256
        int B0 = 4095 - b - nb;
        int ofs = B0 + 8*q;
        dwb = ((ofs & 1) ? AREV_DW : 0) + (ofs >> 1);
        #pragma unroll
        for (int j = 1; j < 8; ++j) rg[8 - j] = LFA(-32*j);
        rg[0] = LFA(0);
        rn  = LFA(32);
        rn2 = LFA(64);
        #pragma unroll
        for (int j = 0; j < 8; ++j) acc[j] = (float4v){0.f,0.f,0.f,0.f};
    };
    auto store_acc = [&]() {
        #pragma unroll
        for (int j = 0; j < 8; ++j) {
            #pragma unroll
            for (int rr = 0; rr < 4; ++rr) {
                int t2 = bW - tsh + 32*j + 4*q + rr;
                obase[(size_t)t2*DIM] = acc[j][rr];
            }
        }
    };

    // prologue: A-writes + first two B stages in flight, then barrier, then init.
    stg(0); stg(1);
    asm volatile("s_waitcnt vmcnt(4) lgkmcnt(0)" ::: "memory");  // lgkm: A-writes done
    __builtin_amdgcn_sched_barrier(0);
    __builtin_amdgcn_s_barrier();
    init_phase((p << 10) + 256*w + 16);

    for (int t = 0; t < WT; ++t) {
        if (t + 2 < WT) stg(t + 2);
        // counted wait: forces stage(t) (+anything older) done; leaves the 2
        // newest stages (4 glds) in flight across the barrier.
        if (t < WT - 2) asm volatile("s_waitcnt vmcnt(4) lgkmcnt(0)" ::: "memory");
        else            asm volatile("s_waitcnt vmcnt(0) lgkmcnt(0)" ::: "memory");
        __builtin_amdgcn_sched_barrier(0);
        __builtin_amdgcn_s_barrier();

        if (t == W1) {                 // phase switch: store band-p acc, init band-(3-p)
            store_acc();
            init_phase(((3 - p) << 10) + 256*(3 - w) + 16);
        }

        int S = ((t < W1) ? t : t - W1) << 8;
        if (S < s_end) {               // wave-uniform; idle waves still barrier
            int bb = (t & 3) * 512;
            short8 b0 = LFB(bb, 0), b1 = LFB(bb, 1);   // depth-2 B pipeline
            #pragma unroll
            for (int u = 0; u < 8; ++u) {
                short8 nr2 = LFA(S + 32*u + 96);       // A prefetch (depth-3)
                short8 bcur = (u & 1) ? b1 : b0;
                short8 bnew;
                if (u < 6) bnew = LFB(bb, u + 2);      // B prefetch (depth-2)
                #pragma unroll
                for (int j = 7; j >= 0; --j)
                    acc[j] = __builtin_amdgcn_mfma_f32_16x16x32_bf16(
                        rg[(u - j) & 7], bcur, acc[j], 0, 0, 0);
                rg[(u + 1) & 7] = rn;  // ring: compile-time renaming, no v_movs
                rn = rn2; rn2 = nr2;
                if (u < 6) { if (u & 1) b1 = bnew; else b0 = bnew; }
            }
        }
    }
    store_acc();
}

extern "C" void kernel_launch(void* const* d_in, const int* in_sizes, int n_in,
                              void* d_out, int out_size, void* d_ws, size_t ws_size,
                              hipStream_t stream) {
    const float* x     = (const float*)d_in[0];
    const float* zero  = (const float*)d_in[1];
    const float* pos   = (const float*)d_in[2];
    const float* gamma = (const float*)d_in[3];
    float* out = (float*)d_out;

    unsigned short* arev = (unsigned short*)d_ws;                 // 512*4448*2 = 4.56 MB
    unsigned short* xp   = arev + (size_t)HD*AREV_LEN;            // 512*8*4144*2 = 33.9 MB

    build_arev<<<dim3(64, 8), 256, 0, stream>>>(zero, pos, gamma, arev);
    build_xp<<<dim3(64, 8, 8), 256, 0, stream>>>(x, xp);
    toeplitz_gemm<<<dim3(1024), 256, 0, stream>>>(arev, xp, out);
}

// Round 7
// 237.842 us; speedup vs baseline: 1.0174x; 1.0174x over previous
//
#include <hip/hip_runtime.h>

#define H 8
#define NSEQ 4096
#define DIM 64
#define BATCH 8
#define AREV_LEN 4448   // 4096 lags + 352 zero pad. 2224 dwords == 16 mod 32 -> shifted
                        // copy sits at bank offset +16 vs base: parity groups disjoint.
#define AREV_DW (AREV_LEN/2)   // 2224
#define XPLEN 4144      // 16 front zeros (shifted-col reads) + 4096 + 32 tail pad.
#define HD (H*DIM)      // 512

typedef __attribute__((ext_vector_type(8))) short short8;
typedef __attribute__((ext_vector_type(4))) float float4v;
typedef __attribute__((ext_vector_type(4))) unsigned int uint4v;
typedef const __attribute__((address_space(1))) unsigned int* gas_u32p;
typedef __attribute__((address_space(3))) unsigned int* las_u32p;

template<int V> struct ic { static constexpr int value = V; };

__device__ inline unsigned short f32_to_bf16(float f) {
    unsigned int u = __float_as_uint(f);
    u += 0x7fffu + ((u >> 16) & 1u);   // RNE
    return (unsigned short)(u >> 16);
}

// ---- P1: arev[hd][i] = bf16( exp(clamp(log(gamma)*k + pos[k-1])) ) at k = 4095 - i ----
__global__ __launch_bounds__(256) void build_arev(
    const float* __restrict__ zero, const float* __restrict__ pos,
    const float* __restrict__ gamma, unsigned short* __restrict__ arev)
{
    __shared__ float lg[64];
    __shared__ unsigned short T[64][65];
    int h = blockIdx.y, kb = blockIdx.x;
    int tid = threadIdx.x;
    if (tid < 64) lg[tid] = logf(gamma[h*64 + tid]);
    __syncthreads();
    #pragma unroll
    for (int jj = 0; jj < 16; ++jj) {
        int e = tid + 256*jj;
        int kk = e >> 6, dd = e & 63;
        int k = kb*64 + kk;
        float v;
        if (k == 0) v = zero[h*64 + dd];
        else        v = lg[dd] * (float)k + pos[(h*4095 + (k-1))*64 + dd];
        v = fminf(30.f, fmaxf(-60.f, v));
        T[kk][dd] = f32_to_bf16(expf(v));
    }
    __syncthreads();
    int i0 = 4032 - kb*64;   // tile writes arev[hd][i0 .. i0+63], i = 4095 - k
    #pragma unroll
    for (int jj = 0; jj < 16; ++jj) {
        int e = tid + 256*jj;
        int dpr = e >> 6, ii = e & 63;
        arev[(size_t)(h*64 + dpr)*AREV_LEN + i0 + ii] = T[63 - ii][dpr];
    }
    unsigned short* pr = arev + (size_t)(h*64 + kb)*AREV_LEN + 4096;
    for (int i = tid; i < AREV_LEN - 4096; i += 256) pr[i] = 0;
}

// ---- P2: xp[hd][b][16 + s] = bf16(x[b][h][s][d]); rows front/tail zero-padded ----
__global__ __launch_bounds__(256) void build_xp(
    const float* __restrict__ x, unsigned short* __restrict__ xp)
{
    __shared__ unsigned short T[64][66];   // stride 66: dword-aligned, conflict-free cols
    int sb = blockIdx.x, h = blockIdx.y, b = blockIdx.z;
    int tid = threadIdx.x;
    const float4v* src4 =
        (const float4v*)(x + ((size_t)(b*H + h)*NSEQ + sb*64)*DIM);
    #pragma unroll
    for (int jj = 0; jj < 4; ++jj) {
        int e = tid + 256*jj;            // [0,1024)
        int ss = e >> 4, d4 = e & 15;
        float4v f = src4[ss*16 + d4];
        #pragma unroll
        for (int k = 0; k < 4; ++k) T[ss][4*d4 + k] = f32_to_bf16(f[k]);
    }
    __syncthreads();
    unsigned int* xp32 = (unsigned int*)xp;
    #pragma unroll
    for (int jj = 0; jj < 8; ++jj) {
        int e = tid + 256*jj;            // [0,2048)
        int dpr = e >> 5, c2 = e & 31;   // row d, dword col (2 s-elems)
        unsigned int lo = T[2*c2][dpr], hi = T[2*c2 + 1][dpr];
        size_t dwofs = (((size_t)(h*64 + dpr)*BATCH + b)*XPLEN + 16 + sb*64) >> 1;
        xp32[dwofs + c2] = lo | (hi << 16);
    }
    if (sb == 0) {
        for (int e = tid; e < 64*16; e += 256) {
            int dd = e >> 4, i = e & 15;
            xp[((size_t)(h*64 + dd)*BATCH + b)*XPLEN + i] = 0;
        }
    }
    if (sb == 63) {
        for (int e = tid; e < 64*32; e += 256) {
            int dd = e >> 5, i = e & 31;
            xp[((size_t)(h*64 + dd)*BATCH + b)*XPLEN + 16 + NSEQ + i] = 0;
        }
    }
}

// ---- GEMM: per (h,d): Out[t, 0:8] = sum_s a[t-s] * X[s, 0:8], causal ----
// One WG = one (h,d) + band pair {p,3-p}; every wave exactly 136 k-steps.
// 20 windows of 256 s, quad-buffered B tiles staged 2 ahead (global_load_lds
// w16, counted vmcnt(4) -- never a full drain mid-loop). Per window: batch-read
// all 8 B-frags (8 x ds_read_b128, XOR-swizzled, conflict-free), then 8 MFMA
// groups of 8; behind each group issue ONE next-window A-frag read into a
// 16-slot STATICALLY-indexed ring (window-pair unroll makes all slot indices
// compile-time). Loads for every operand are issued a full window (~1200 cyc)
// before use -> one lgkm exposure per 64 MFMAs. __launch_bounds__(256,2)
// lifts the VGPR cap so the ~145-reg working set stays in registers (previous
// rounds compiled at 56-80 VGPR < live set: allocator sank loads to uses,
// serializing ~5 x 120cyc LDS latency per 8-MFMA step -- the flat ~127us wall).
__global__ __launch_bounds__(256, 2) void toeplitz_gemm(
    const unsigned short* __restrict__ arev,
    const unsigned short* __restrict__ xp,
    float* __restrict__ out)
{
    __shared__ unsigned int ldsA[2*AREV_DW];   // 17.8 KB: arev dwords + 1-elem shift
    __shared__ uint4v ldsB[4*512];             // 32 KB: quad-buffered 8KB B tiles

    // swizzle: 16 line-sharing consecutive-d WGs -> same XCD (id%8).
    int id = blockIdx.x;                 // [0, 1024)
    int q8 = id >> 7, rem = id & 127;
    int r  = rem >> 3, xx = rem & 7;
    int g  = q8*8 + xx;                  // [0, 64)
    int nlin = g*16 + r;                 // [0, 1024)
    int p  = nlin >> 9;                  // band pair: {p, 3-p}
    int h  = (nlin >> 6) & 7;
    int d  = nlin & 63;
    int hd = h*64 + d;

    int tid = threadIdx.x;
    const unsigned int* g32 = (const unsigned int*)(arev + (size_t)hd*AREV_LEN);
    int i0s = p << 9;                    // pair {1,2} never reads lag idx < 1024
    for (int i = i0s + tid; i < AREV_DW; i += 256) ldsA[i] = g32[i];
    for (int i = i0s + tid; i < AREV_DW - 1; i += 256)
        ldsA[AREV_DW + i] = (g32[i] >> 16) | (g32[i+1] << 16);  // elems 2i+1, 2i+2

    int w = tid >> 6, lane = tid & 63;
    int nb = lane & 15;        // A-frag row m and B-frag col n
    int q  = lane >> 4;        // k-quad
    int swz  = (nb >> 1) & 3;
    int bq16 = nb*4 + (q ^ swz);   // swizzled B-frag uint4 index within a chunk

    // staging: lane l stages piece (chunk c, row l>>2, q'=l&3); source elem =
    // S + 128c + 32w + 8*(q' ^ swz(row)); LDS written linearly (swizzle folded
    // into the GLOBAL source so reads at bq16 are conflict-free).
    int rnb = lane >> 2, rq = lane & 3, rswz = (rnb >> 1) & 3;
    const unsigned short* xsrc =
        xp + ((size_t)hd*BATCH + (rnb & 7))*XPLEN + 16 - ((rnb >> 3) << 4)
           + w*32 + 8*(rq ^ rswz);

    int W1 = (p + 1) * 4;      // phase-1 windows; WT = 20 for both pairs
    const int WT = 20;

    auto stg = [&](int t) {
        int S = ((t < W1) ? t : t - W1) << 8;
        __builtin_amdgcn_global_load_lds(
            (gas_u32p)(const void*)(xsrc + S),
            (las_u32p)(void*)&ldsB[(t & 3)*512 + w*64], 16, 0, 0);
        __builtin_amdgcn_global_load_lds(
            (gas_u32p)(const void*)(xsrc + S + 128),
            (las_u32p)(void*)&ldsB[(t & 3)*512 + 256 + w*64], 16, 0, 0);
    };

    int tsh = (nb >> 3) << 4;
    float* obase = out + ((size_t)((nb & 7)*H + h)*NSEQ)*DIM + d;

    // persistent per-phase state -- ALL statically indexed (stays in VGPRs)
    float4v acc[8];            // 32 VGPR
    short8  aw[16];            // 64 VGPR: A-frag ring, slot = (7 + u - j + 8t) & 15
    int dwb = 0, s_end = 0, bW = 0;

    auto LFA = [&](int so) -> short8 {
        int dw = dwb + (so >> 1);    // so always even; parity folded into dwb
        union { short8 v; unsigned int u4[4]; } af;
        af.u4[0] = ldsA[dw];   af.u4[1] = ldsA[dw+1];
        af.u4[2] = ldsA[dw+2]; af.u4[3] = ldsA[dw+3];
        return af.v;
    };
    auto LFB = [&](int bb, int u) -> short8 {
        union { short8 v; uint4v u4; } bf_;
        bf_.u4 = ldsB[bb + u*64 + bq16];   // single ds_read_b128, 16B-aligned
        return bf_.v;
    };

    auto init_phase = [&](int b) {   // only called at windows with map M == 0
        bW = b;
        s_end = b + 240;             // multiple of 256
        int B0 = 4095 - b - nb;
        int ofs = B0 + 8*q;
        dwb = ((ofs & 1) ? AREV_DW : 0) + (ofs >> 1);
        #pragma unroll
        for (int k = -7; k <= 7; ++k) aw[(7 + k) & 15] = LFA(32*k);
        #pragma unroll
        for (int j = 0; j < 8; ++j) acc[j] = (float4v){0.f,0.f,0.f,0.f};
    };
    auto store_acc = [&]() {
        #pragma unroll
        for (int j = 0; j < 8; ++j) {
            #pragma unroll
            for (int rr = 0; rr < 4; ++rr) {
                int t2 = bW - tsh + 32*j + 4*q + rr;
                obase[(size_t)t2*DIM] = acc[j][rr];
            }
        }
    };

    // prologue: A-writes visible, first two B stages in flight, then init.
    stg(0); stg(1);
    asm volatile("s_waitcnt vmcnt(4) lgkmcnt(0)" ::: "memory");
    __builtin_amdgcn_sched_barrier(0);
    __builtin_amdgcn_s_barrier();
    init_phase((p << 10) + 256*w + 16);

    auto window = [&](int t, auto mtag) {
        constexpr int M = decltype(mtag)::value;   // (8t) & 15
        if (t + 2 < WT) stg(t + 2);
        if (t < WT - 2) asm volatile("s_waitcnt vmcnt(4)" ::: "memory");
        else            asm volatile("s_waitcnt vmcnt(0)" ::: "memory");
        __builtin_amdgcn_sched_barrier(0);
        __builtin_amdgcn_s_barrier();

        if constexpr (M == 0) {      // phase switch only at even windows (W1 even)
            if (t == W1) {
                store_acc();
                init_phase(((3 - p) << 10) + 256*(3 - w) + 16);
            }
        }

        int S = ((t < W1) ? t : t - W1) << 8;
        if (S < s_end) {             // wave-uniform; idle waves still barrier
            int bb = (t & 3) * 512;
            short8 B8[8];
            #pragma unroll
            for (int u = 0; u < 8; ++u) B8[u] = LFB(bb, u);
            #pragma unroll
            for (int u = 0; u < 8; ++u) {
                #pragma unroll
                for (int j = 7; j >= 0; --j)
                    acc[j] = __builtin_amdgcn_mfma_f32_16x16x32_bf16(
                        aw[(7 + u - j + M) & 15], B8[u], acc[j], 0, 0, 0);
                // next window's A-frag; target slot was last consumed at group u
                aw[(15 + u + M) & 15] = LFA(S + 256 + 32*u);
            }
        }
    };

    for (int tp = 0; tp < 10; ++tp) {   // window pairs: slot maps M = 0, 8
        window(2*tp,     ic<0>{});
        window(2*tp + 1, ic<8>{});
    }
    store_acc();
}

extern "C" void kernel_launch(void* const* d_in, const int* in_sizes, int n_in,
                              void* d_out, int out_size, void* d_ws, size_t ws_size,
                              hipStream_t stream) {
    const float* x     = (const float*)d_in[0];
    const float* zero  = (const float*)d_in[1];
    const float* pos   = (const float*)d_in[2];
    const float* gamma = (const float*)d_in[3];
    float* out = (float*)d_out;

    unsigned short* arev = (unsigned short*)d_ws;                 // 512*4448*2 = 4.56 MB
    unsigned short* xp   = arev + (size_t)HD*AREV_LEN;            // 512*8*4144*2 = 33.9 MB

    build_arev<<<dim3(64, 8), 256, 0, stream>>>(zero, pos, gamma, arev);
    build_xp<<<dim3(64, 8, 8), 256, 0, stream>>>(x, xp);
    toeplitz_gemm<<<dim3(1024), 256, 0, stream>>>(arev, xp, out);
}